// Round 7
// baseline (200.846 us; speedup 1.0000x reference)
//
#include <hip/hip_runtime.h>
#include <hip/hip_bf16.h>

// Problem: B=64, S=512, D=512.
// out[b] = (sum_{valid i} max_{valid j} sim[i,j] + sum_{valid j} max_{valid i} sim[i,j]) / (n1+n2)
// sim = normalize(e1) @ normalize(e2)^T per batch.
//
// Round-14: halve the barrier-phase count. Evidence chain: r5->r6 halved
// staging work + doubled occupancy -> NULL; r3 halved occupancy -> +50%;
// fetch fix -> only -7%. Every throughput axis is cleared; the residual
// model is per-phase fixed overhead (barrier convoy + lgkm drain + restart
// + ds_read->MFMA latency), ~2.6k cyc/phase vs ~700 of work. So: BK 32->64,
// 8 phases instead of 16, identical per-K work density:
//   * 128x128 tile, 16x16x32 MFMA (layout unchanged, proven r2-r13)
//   * LDS 64 KB: sA[2][128*64] + sB[2][128*64] bf16, double-buffered
//     -> 2 blocks/CU (16 waves/CU, the TLP level r6 proved sufficient)
//   * 512 thr: waves 0-3 stage A, 4-7 stage B; 32 floats/thread/phase
//     (8 float4), single-deep reg prefetch to stay under 128-VGPR cliff
//   * 3-bit XOR swizzle: chunk c (8 bf16) of row r at slot c ^ s3(r),
//     s3(r) = ((r>>3) ^ r) & 7, row stride 64 ushorts
//   * lgkm-only barriers, XCD-batch-affinity swizzle kept (proven)
// ws: 1 MB (partial maxes only).

typedef __attribute__((ext_vector_type(8))) short bf16x8;   // 8 bf16 in 4 VGPRs
typedef __attribute__((ext_vector_type(4))) float f32x4;

#define NEGBIG (-1e9f)

__device__ __forceinline__ unsigned packbf2_hw(float lo, float hi) {
    __hip_bfloat162 h = __float22bfloat162_rn(float2{lo, hi});
    union { __hip_bfloat162 h; unsigned u; } c; c.h = h;
    return c.u;
}

// Barrier with LDS-only drain: global loads (private reg dests) stay in
// flight across it. "memory" clobbers fence compiler code motion both sides.
#define BAR() do {                                            \
        asm volatile("s_waitcnt lgkmcnt(0)" ::: "memory");    \
        __builtin_amdgcn_s_barrier();                         \
        asm volatile("" ::: "memory");                        \
    } while (0)

// ---------------- kernel 1: fused cast+norm+GEMM+masked-max ----------------
// grid: 1024 blocks (1-D, XCD-swizzled), 512 thr = 8 waves (2x4 of 64x32).
// Tile 128x128, BK=64, 8 phases, double-buffered bf16 LDS via ds_write.
__global__ __launch_bounds__(512)
void sim_fused(const float* __restrict__ e1, const float* __restrict__ e2,
               const int* __restrict__ m1g, const int* __restrict__ m2g,
               float* __restrict__ rowmax_p,   // [B][4][512]
               float* __restrict__ colmax_p)   // [B][4][512]
{
    // ---- XCD-batch-affinity decode: XCD (bid%8) owns 8 consecutive batches.
    const int bid = blockIdx.x;
    const int l   = ((bid & 7) << 7) | (bid >> 3);   // bijective, 1024 = 8*128
    const int b   = l >> 4;
    const int rt  = l & 3;
    const int ct  = (l >> 2) & 3;

    const int tid  = threadIdx.x;
    const int lane = tid & 63;
    const int w    = tid >> 6;        // 0..7
    const int wm   = w >> 2;          // 0..1  (64-row half)
    const int wn   = w & 3;           // 0..3  (32-col quarter)
    const int q    = lane >> 4;
    const int ln   = lane & 15;
    const int nb   = ct * 128;        // global col base

    __shared__ __align__(16) ushort sA[2][128 * 64];   // 2 x 16 KB
    __shared__ __align__(16) ushort sB[2][128 * 64];   // 2 x 16 KB
    // Epilogue aliases into parity-0 tile space (dead after the k-loop).
    float* spr   = reinterpret_cast<float*>(&sA[0][0]);      // [4][128]
    float* spc   = reinterpret_cast<float*>(&sA[0][1024]);   // [2][128]
    int*   sm1   = reinterpret_cast<int*>(&sA[0][1536]);     // [128]
    int*   sm2   = reinterpret_cast<int*>(&sA[0][1792]);     // [128]
    float* sinv1 = reinterpret_cast<float*>(&sB[0][0]);      // [128]
    float* sinv2 = reinterpret_cast<float*>(&sB[0][256]);    // [128]

    // ---- staging: waves 0-3 stage A, waves 4-7 stage B. Within each group,
    // thread (r = tt>>1, h = tt&1) covers row r, k-local [h*32, h*32+32).
    const int  tt  = tid & 255;
    const int  r   = tt >> 1;
    const int  h   = tt & 1;
    const int  s3r = ((r >> 3) ^ r) & 7;
    const bool isA = (tid < 256);     // wave-uniform
    const float* gsrc = (isA
        ? e1 + ((size_t)(b * 512 + rt * 128 + r)) * 512
        : e2 + ((size_t)(b * 512 + nb + r)) * 512) + h * 32;
    ushort* const wb0 = isA ? &sA[0][0] : &sB[0][0];
    ushort* const wb1 = isA ? &sA[1][0] : &sB[1][0];
    // chunk c = 4h+j (8 bf16 each) -> slot c ^ s3(r) (ushort offsets)
    int wo[4];
    #pragma unroll
    for (int j = 0; j < 4; ++j)
        wo[j] = r * 64 + (((4 * h + j) ^ s3r) << 3);

    // ---- fragment read offsets: row = base16 + ln, chunk = ks*4 + q,
    // slot = chunk ^ s3(row). Precompute all 12.
    int aoff[4][2], boff[2][2];
    #pragma unroll
    for (int mt = 0; mt < 4; ++mt) {
        const int row = wm * 64 + mt * 16 + ln;
        const int s3  = ((row >> 3) ^ row) & 7;
        #pragma unroll
        for (int ks = 0; ks < 2; ++ks)
            aoff[mt][ks] = row * 64 + (((ks * 4 + q) ^ s3) << 3);
    }
    #pragma unroll
    for (int nt = 0; nt < 2; ++nt) {
        const int col = wn * 32 + nt * 16 + ln;
        const int s3  = ((col >> 3) ^ col) & 7;
        #pragma unroll
        for (int ks = 0; ks < 2; ++ks)
            boff[nt][ks] = col * 64 + (((ks * 4 + q) ^ s3) << 3);
    }

    float ss = 0.f;
    float4 rg_[8];                    // single-deep staging regs (32 floats)

    auto LOADK = [&](int kf) {        // kf = float offset of 64-float chunk
        const float4* p = reinterpret_cast<const float4*>(gsrc + kf);
        #pragma unroll
        for (int j = 0; j < 8; ++j) rg_[j] = p[j];
    };
    auto CVTWRITE = [&](ushort* wb) {
        #pragma unroll
        for (int i = 0; i < 8; ++i) {
            ss += rg_[i].x * rg_[i].x + rg_[i].y * rg_[i].y
                + rg_[i].z * rg_[i].z + rg_[i].w * rg_[i].w;
        }
        #pragma unroll
        for (int j = 0; j < 4; ++j) {
            uint4 v;
            v.x = packbf2_hw(rg_[2*j].x,   rg_[2*j].y);
            v.y = packbf2_hw(rg_[2*j].z,   rg_[2*j].w);
            v.z = packbf2_hw(rg_[2*j+1].x, rg_[2*j+1].y);
            v.w = packbf2_hw(rg_[2*j+1].z, rg_[2*j+1].w);
            *reinterpret_cast<uint4*>(wb + wo[j]) = v;
        }
    };

    f32x4 acc[4][2];
    #pragma unroll
    for (int i = 0; i < 4; ++i)
        #pragma unroll
        for (int j = 0; j < 2; ++j)
            acc[i][j] = (f32x4){0.f, 0.f, 0.f, 0.f};

    // prologue: tile 0 -> LDS buf0; tile 1 -> regs
    LOADK(0);
    CVTWRITE(wb0);
    LOADK(64);
    BAR();

    // Phase T (LDS parity P = T&1): buf[P] holds tile T, regs hold tile T+1.
    //   frags ks=0 from buf[P]; cvt+write tile T+1 -> buf[P^1];
    //   issue loads tile T+2 -> regs; MFMA ks0; frags ks=1; MFMA ks1; BAR.
#define PHASE(P, T)                                                        \
    do {                                                                   \
        bf16x8 af[4], bfr[2];                                              \
        _Pragma("unroll")                                                  \
        for (int mt = 0; mt < 4; ++mt)                                     \
            af[mt] = *reinterpret_cast<const bf16x8*>(&sA[P][aoff[mt][0]]);\
        _Pragma("unroll")                                                  \
        for (int nt = 0; nt < 2; ++nt)                                     \
            bfr[nt] = *reinterpret_cast<const bf16x8*>(&sB[P][boff[nt][0]]);\
        if ((T) < 7) CVTWRITE((P) ? wb0 : wb1);                            \
        if ((T) < 6) LOADK(((T) + 2) * 64);                                \
        _Pragma("unroll")                                                  \
        for (int mt = 0; mt < 4; ++mt)                                     \
            _Pragma("unroll")                                              \
            for (int nt = 0; nt < 2; ++nt)                                 \
                acc[mt][nt] = __builtin_amdgcn_mfma_f32_16x16x32_bf16(     \
                    af[mt], bfr[nt], acc[mt][nt], 0, 0, 0);                \
        _Pragma("unroll")                                                  \
        for (int mt = 0; mt < 4; ++mt)                                     \
            af[mt] = *reinterpret_cast<const bf16x8*>(&sA[P][aoff[mt][1]]);\
        _Pragma("unroll")                                                  \
        for (int nt = 0; nt < 2; ++nt)                                     \
            bfr[nt] = *reinterpret_cast<const bf16x8*>(&sB[P][boff[nt][1]]);\
        _Pragma("unroll")                                                  \
        for (int mt = 0; mt < 4; ++mt)                                     \
            _Pragma("unroll")                                              \
            for (int nt = 0; nt < 2; ++nt)                                 \
                acc[mt][nt] = __builtin_amdgcn_mfma_f32_16x16x32_bf16(     \
                    af[mt], bfr[nt], acc[mt][nt], 0, 0, 0);                \
        BAR();                                                             \
    } while (0)

    for (int kk = 0; kk < 4; ++kk) {
        PHASE(0, 2 * kk);
        PHASE(1, 2 * kk + 1);
    }
#undef PHASE

    // ---- masks into dead parity-0 tile space; finish norms.
    // thread pair (2r, 2r+1) holds half-row sums of its matrix's row r.
    if (tid < 128)      sm1[tid]       = m1g[b * 512 + rt * 128 + tid];
    else if (tid < 256) sm2[tid - 128] = m2g[b * 512 + nb + (tid - 128)];
    ss += __shfl_xor(ss, 1);
    if (h == 0) {
        float inv = 1.0f / fmaxf(sqrtf(ss), 1e-8f);
        if (isA) sinv1[r] = inv;
        else     sinv2[r] = inv;
    }
    BAR();

    // ---- scale: sim = acc * inv_i * inv_j (C/D layout: col=ln, row=q*4+reg)
    float invj[2];
    f32x4 invi[4];
    #pragma unroll
    for (int nt = 0; nt < 2; ++nt)
        invj[nt] = sinv2[wn * 32 + nt * 16 + ln];
    #pragma unroll
    for (int mt = 0; mt < 4; ++mt)
        #pragma unroll
        for (int rg = 0; rg < 4; ++rg)
            invi[mt][rg] = sinv1[wm * 64 + mt * 16 + q * 4 + rg];
    #pragma unroll
    for (int mt = 0; mt < 4; ++mt)
        #pragma unroll
        for (int nt = 0; nt < 2; ++nt)
            acc[mt][nt] = acc[mt][nt] * (invi[mt] * invj[nt]);

    // ---- masked row maxes (this wave's 32 cols; combined across wn via spr)
    #pragma unroll
    for (int mt = 0; mt < 4; ++mt) {
        #pragma unroll
        for (int rg = 0; rg < 4; ++rg) {
            float rm = NEGBIG;
            #pragma unroll
            for (int nt = 0; nt < 2; ++nt) {
                float v = sm2[wn * 32 + nt * 16 + ln] ? acc[mt][nt][rg] : NEGBIG;
                rm = fmaxf(rm, v);
            }
            rm = fmaxf(rm, __shfl_xor(rm, 1));
            rm = fmaxf(rm, __shfl_xor(rm, 2));
            rm = fmaxf(rm, __shfl_xor(rm, 4));
            rm = fmaxf(rm, __shfl_xor(rm, 8));
            if (ln == 0) spr[wn * 128 + wm * 64 + mt * 16 + q * 4 + rg] = rm;
        }
    }
    // ---- masked col maxes (this wave's 64 rows; combined across wm via spc)
    #pragma unroll
    for (int nt = 0; nt < 2; ++nt) {
        float cm = NEGBIG;
        #pragma unroll
        for (int mt = 0; mt < 4; ++mt)
            #pragma unroll
            for (int rg = 0; rg < 4; ++rg) {
                float v = sm1[wm * 64 + mt * 16 + q * 4 + rg] ? acc[mt][nt][rg] : NEGBIG;
                cm = fmaxf(cm, v);
            }
        cm = fmaxf(cm, __shfl_xor(cm, 16));
        cm = fmaxf(cm, __shfl_xor(cm, 32));
        if (lane < 16) spc[wm * 128 + wn * 32 + nt * 16 + ln] = cm;
    }
    BAR();
    if (tid < 128) {
        rowmax_p[((size_t)b * 4 + ct) * 512 + rt * 128 + tid] =
            fmaxf(fmaxf(spr[tid], spr[128 + tid]),
                  fmaxf(spr[256 + tid], spr[384 + tid]));
        colmax_p[((size_t)b * 4 + rt) * 512 + nb + tid] =
            fmaxf(spc[tid], spc[128 + tid]);
    }
}

// ---------------- kernel 2: per-batch final reduction ----------------
__global__ __launch_bounds__(256)
void final_kernel(const int* __restrict__ m1g, const int* __restrict__ m2g,
                  const float* __restrict__ rowmax_p, const float* __restrict__ colmax_p,
                  float* __restrict__ out)
{
    const int b = blockIdx.x;
    const int tid = threadIdx.x;
    const int lane = tid & 63;
    const int w = tid >> 6;

    float sum = 0.f;
    float nn  = 0.f;
    for (int j = tid; j < 512; j += 256) {
        int mm1 = m1g[b * 512 + j];
        int mm2 = m2g[b * 512 + j];
        nn += (float)(mm1 + mm2);
        const float* rp = rowmax_p + (size_t)b * 2048 + j;
        float rm = fmaxf(fmaxf(rp[0], rp[512]), fmaxf(rp[1024], rp[1536]));
        if (mm1) sum += rm;
        const float* cp = colmax_p + (size_t)b * 2048 + j;
        float cm = fmaxf(fmaxf(cp[0], cp[512]), fmaxf(cp[1024], cp[1536]));
        if (mm2) sum += cm;
    }
    #pragma unroll
    for (int m = 32; m; m >>= 1) {
        sum += __shfl_xor(sum, m);
        nn  += __shfl_xor(nn, m);
    }
    __shared__ float ssum[4], snn[4];
    if (lane == 0) { ssum[w] = sum; snn[w] = nn; }
    __syncthreads();
    if (tid == 0) {
        float S = ssum[0] + ssum[1] + ssum[2] + ssum[3];
        float N = snn[0] + snn[1] + snn[2] + snn[3];
        out[b] = S / N;
    }
}

extern "C" void kernel_launch(void* const* d_in, const int* in_sizes, int n_in,
                              void* d_out, int out_size, void* d_ws, size_t ws_size,
                              hipStream_t stream) {
    const float* e1 = (const float*)d_in[0];
    const float* e2 = (const float*)d_in[1];
    const int*   m1 = (const int*)d_in[2];
    const int*   m2 = (const int*)d_in[3];
    float* out = (float*)d_out;

    float* ws = (float*)d_ws;             // 1 MB
    float* rowmax_p = ws;                 // 64*4*512
    float* colmax_p = ws + 131072;        // 64*4*512

    sim_fused<<<dim3(1024), 512, 0, stream>>>(e1, e2, m1, m2,
                                              rowmax_p, colmax_p);
    final_kernel<<<64, 256, 0, stream>>>(m1, m2, rowmax_p, colmax_p, out);
}

// Round 8
// 193.915 us; speedup vs baseline: 1.0357x; 1.0357x over previous
//
#include <hip/hip_runtime.h>
#include <hip/hip_bf16.h>

// Problem: B=64, S=512, D=512.
// out[b] = (sum_{valid i} max_{valid j} sim[i,j] + sum_{valid j} max_{valid i} sim[i,j]) / (n1+n2)
// sim = normalize(e1) @ normalize(e2)^T per batch.
//
// Round-15: split prep from GEMM. Six rounds of evidence: r5 (fused,
// 69.7us) is the fused structure's floor; staging/occupancy/fetch/barrier
// probes all null or small; r6/r7 show the compiler's VGPR tiering keeps
// breaking reg-staged prefetch (60-64 VGPR -> loads sink into the phase).
// The fix is staging with NO registers at all: global_load_lds (T3 2-phase,
// m97-proven 874TF at this tile size). That requires bf16 inputs, so:
//   prep_kernel: normalize (fp32, matches reference) + cast -> bf16 panels
//     in ws, PRE-SWIZZLED so linear global_load_lds reproduces r5's proven
//     LDS layout (rule 21: inverse-swizzle source, linear dest).
//     XCD-affine: each XCD preps+consumes its own 8 batches (8.4MB, L2-fit).
//   sim_gemm: r5 geometry (256thr, 128x128 tile, BK=32, same frag offsets,
//     same masked-max epilogue minus norm scaling); staging = 4
//     global_load_lds_dwordx4/thread/iter; loop = STAGE(next) -> ds_read ->
//     MFMA -> vmcnt(0) -> barrier (T3 minimum pipeline).
//   Fallback: if ws_size < 68.2MB, run the r5 fused kernel unchanged.
// ws: 1 MB partials + 64 MB bf16 panels.

typedef __attribute__((ext_vector_type(8))) short bf16x8;   // 8 bf16 in 4 VGPRs
typedef __attribute__((ext_vector_type(4))) float f32x4;

#define NEGBIG (-1e9f)

__device__ __forceinline__ unsigned packbf2_hw(float lo, float hi) {
    __hip_bfloat162 h = __float22bfloat162_rn(float2{lo, hi});
    union { __hip_bfloat162 h; unsigned u; } c; c.h = h;
    return c.u;
}

// lgkm-only barrier (fused path; ds_write visibility, globals stay in flight)
#define BAR() do {                                            \
        asm volatile("s_waitcnt lgkmcnt(0)" ::: "memory");    \
        __builtin_amdgcn_s_barrier();                         \
        asm volatile("" ::: "memory");                        \
    } while (0)

// vmcnt-drain barrier (gload_lds path: DMA completion is tracked by vmcnt;
// ds_read completion enforced by compiler before MFMA use)
#define BARV() do {                                           \
        asm volatile("s_waitcnt vmcnt(0)" ::: "memory");      \
        __builtin_amdgcn_s_barrier();                         \
        asm volatile("" ::: "memory");                        \
    } while (0)

__device__ __forceinline__ void glds16(const ushort* g, ushort* l) {
    __builtin_amdgcn_global_load_lds(
        (const __attribute__((address_space(1))) unsigned int*)(const void*)g,
        (__attribute__((address_space(3))) unsigned int*)(void*)l,
        16, 0, 0);
}

// ---------------- kernel 0: normalize + cast + pre-swizzle ----------------
// grid 1024 (XCD-swizzled), 256 thr. Block = (batch b, idx): idx<8 -> e1 rows
// [(idx&7)*64, +64), else e2. One wave per row (16 rows/wave sequential).
// Output chunk c (8 bf16) of row r stored at slot c^s(r) within its 32-k
// group, s(r) = (r ^ (r>>2)) & 3  -> linear gload_lds lands r5's LDS layout.
__global__ __launch_bounds__(256)
void prep_kernel(const float* __restrict__ e1, const float* __restrict__ e2,
                 ushort* __restrict__ e1n, ushort* __restrict__ e2n)
{
    const int bid = blockIdx.x;
    const int l   = ((bid & 7) << 7) | (bid >> 3);
    const int b   = l >> 4;
    const int idx = l & 15;
    const int lane = threadIdx.x & 63;
    const int w    = threadIdx.x >> 6;
    const float*  src = (idx < 8) ? e1 : e2;
    ushort*       dst = (idx < 8) ? e1n : e2n;
    const int rbase = (idx & 7) * 64;

    #pragma unroll 4
    for (int i = 0; i < 16; ++i) {
        const int row = rbase + w * 16 + i;
        const size_t off = ((size_t)b * 512 + row) * 512;
        const float4* p = reinterpret_cast<const float4*>(src + off) + lane * 2;
        float4 x = p[0], y = p[1];
        float ss = x.x*x.x + x.y*x.y + x.z*x.z + x.w*x.w
                 + y.x*y.x + y.y*y.y + y.z*y.z + y.w*y.w;
        #pragma unroll
        for (int m = 1; m < 64; m <<= 1) ss += __shfl_xor(ss, m);
        const float inv = 1.0f / fmaxf(sqrtf(ss), 1e-8f);
        x.x *= inv; x.y *= inv; x.z *= inv; x.w *= inv;
        y.x *= inv; y.y *= inv; y.z *= inv; y.w *= inv;
        uint4 v;
        v.x = packbf2_hw(x.x, x.y); v.y = packbf2_hw(x.z, x.w);
        v.z = packbf2_hw(y.x, y.y); v.w = packbf2_hw(y.z, y.w);
        const int s = (row ^ (row >> 2)) & 3;
        *reinterpret_cast<uint4*>(dst + off + (lane >> 2) * 32
                                  + ((lane & 3) ^ s) * 8) = v;
    }
}

// ---------------- kernel 1: bf16 GEMM + masked-max (gload_lds) ----------------
// grid 1024 (XCD-swizzled), 256 thr = 4 waves (2x2 of 64x64). 128x128 tile,
// BK=32, double-buffered LDS staged by global_load_lds dwordx4 (linear dest;
// source pre-swizzled by prep). Frag offsets identical to r5 (proven).
__global__ __launch_bounds__(256)
void sim_gemm(const ushort* __restrict__ e1n, const ushort* __restrict__ e2n,
              const int* __restrict__ m1g, const int* __restrict__ m2g,
              float* __restrict__ rowmax_p, float* __restrict__ colmax_p)
{
    const int bid = blockIdx.x;
    const int l   = ((bid & 7) << 7) | (bid >> 3);
    const int b   = l >> 4;
    const int rt  = l & 3;
    const int ct  = (l >> 2) & 3;

    const int tid  = threadIdx.x;
    const int lane = tid & 63;
    const int w    = tid >> 6;        // 0..3
    const int wm   = w >> 1;
    const int wn   = w & 1;
    const int q    = lane >> 4;
    const int ln   = lane & 15;
    const int nb   = ct * 128;

    __shared__ __align__(16) ushort sA[2][128 * 32];   // 2 x 8 KB
    __shared__ __align__(16) ushort sB[2][128 * 32];   // 2 x 8 KB
    float* spr = reinterpret_cast<float*>(&sA[0][0]);     // [2][128]
    float* spc = reinterpret_cast<float*>(&sA[0][512]);   // [2][128]
    int*   sm1 = reinterpret_cast<int*>(&sA[0][1024]);    // [128]
    int*   sm2 = reinterpret_cast<int*>(&sA[0][1280]);    // [128]

    // ---- staging: wave w stages A-chunks 2w,2w+1 and B-chunks 2w,2w+1.
    // Chunk ch = 16 rows x 32 k (1KB). lane l -> row ch*16+(l>>2),
    // k-ushort (l&3)*8; LDS dest = chunk base + l*16 bytes (linear).
    const int rs = lane >> 2;
    const int ks = (lane & 3) * 8;
    const ushort* gA0 = e1n + ((size_t)(b * 512 + rt * 128 + 2 * w * 16 + rs)) * 512 + ks;
    const ushort* gA1 = gA0 + 16 * 512;
    const ushort* gB0 = e2n + ((size_t)(b * 512 + nb + 2 * w * 16 + rs)) * 512 + ks;
    const ushort* gB1 = gB0 + 16 * 512;
    const int dch = w * 1024;          // chunk-pair base (ushorts)

    // ---- fragment read offsets (identical to r5; slot = chunk ^ s(row))
    const int sln = (ln & 3) ^ ((ln >> 2) & 3);
    int aoff[4], boff[4];
    #pragma unroll
    for (int mt = 0; mt < 4; ++mt)
        aoff[mt] = (wm * 64 + mt * 16 + ln) * 32 + ((q ^ sln) << 3);
    #pragma unroll
    for (int nt = 0; nt < 4; ++nt)
        boff[nt] = (wn * 64 + nt * 16 + ln) * 32 + ((q ^ sln) << 3);

    f32x4 acc[4][4];
    #pragma unroll
    for (int i = 0; i < 4; ++i)
        #pragma unroll
        for (int j = 0; j < 4; ++j)
            acc[i][j] = (f32x4){0.f, 0.f, 0.f, 0.f};

#define STAGE(P2, KT)                                                       \
    do {                                                                    \
        const int k32 = (KT) * 32;                                          \
        glds16(gA0 + k32, &sA[P2][dch]);                                    \
        glds16(gA1 + k32, &sA[P2][dch + 512]);                              \
        glds16(gB0 + k32, &sB[P2][dch]);                                    \
        glds16(gB1 + k32, &sB[P2][dch + 512]);                              \
    } while (0)

    STAGE(0, 0);
    BARV();

#define ITER(P, K)                                                          \
    do {                                                                    \
        if ((K) < 15) STAGE((P) ^ 1, (K) + 1);                              \
        bf16x8 af[4], bfr[4];                                               \
        _Pragma("unroll")                                                   \
        for (int mt = 0; mt < 4; ++mt)                                      \
            af[mt] = *reinterpret_cast<const bf16x8*>(&sA[P][aoff[mt]]);    \
        _Pragma("unroll")                                                   \
        for (int nt = 0; nt < 4; ++nt)                                      \
            bfr[nt] = *reinterpret_cast<const bf16x8*>(&sB[P][boff[nt]]);   \
        _Pragma("unroll")                                                   \
        for (int mt = 0; mt < 4; ++mt)                                      \
            _Pragma("unroll")                                               \
            for (int nt = 0; nt < 4; ++nt)                                  \
                acc[mt][nt] = __builtin_amdgcn_mfma_f32_16x16x32_bf16(      \
                    af[mt], bfr[nt], acc[mt][nt], 0, 0, 0);                 \
        BARV();                                                             \
    } while (0)

    for (int kk = 0; kk < 8; ++kk) {
        ITER(0, 2 * kk);
        ITER(1, 2 * kk + 1);
    }
#undef ITER
#undef STAGE

    // ---- masks into dead tile space (no norm work: inputs pre-normalized)
    if (tid < 128) sm1[tid] = m1g[b * 512 + rt * 128 + tid];
    else           sm2[tid - 128] = m2g[b * 512 + nb + (tid - 128)];
    BAR();

    // ---- masked row maxes (C/D layout: col=ln, row=q*4+reg)
    #pragma unroll
    for (int mt = 0; mt < 4; ++mt) {
        #pragma unroll
        for (int rg = 0; rg < 4; ++rg) {
            float rm = NEGBIG;
            #pragma unroll
            for (int nt = 0; nt < 4; ++nt) {
                float v = sm2[wn * 64 + nt * 16 + ln] ? acc[mt][nt][rg] : NEGBIG;
                rm = fmaxf(rm, v);
            }
            rm = fmaxf(rm, __shfl_xor(rm, 1));
            rm = fmaxf(rm, __shfl_xor(rm, 2));
            rm = fmaxf(rm, __shfl_xor(rm, 4));
            rm = fmaxf(rm, __shfl_xor(rm, 8));
            if (ln == 0) spr[wn * 128 + wm * 64 + mt * 16 + q * 4 + rg] = rm;
        }
    }
    #pragma unroll
    for (int nt = 0; nt < 4; ++nt) {
        float cm = NEGBIG;
        #pragma unroll
        for (int mt = 0; mt < 4; ++mt)
            #pragma unroll
            for (int rg = 0; rg < 4; ++rg) {
                float v = sm1[wm * 64 + mt * 16 + q * 4 + rg] ? acc[mt][nt][rg] : NEGBIG;
                cm = fmaxf(cm, v);
            }
        cm = fmaxf(cm, __shfl_xor(cm, 16));
        cm = fmaxf(cm, __shfl_xor(cm, 32));
        if (lane < 16) spc[wm * 128 + wn * 64 + nt * 16 + ln] = cm;
    }
    BAR();
    if (tid < 128) {
        rowmax_p[((size_t)b * 4 + ct) * 512 + rt * 128 + tid] =
            fmaxf(spr[tid], spr[128 + tid]);
        colmax_p[((size_t)b * 4 + rt) * 512 + nb + tid] =
            fmaxf(spc[tid], spc[128 + tid]);
    }
}

// ---------------- fallback: r5 fused kernel (verbatim) ----------------
__global__ __launch_bounds__(256)
void sim_fused_fb(const float* __restrict__ e1, const float* __restrict__ e2,
                  const int* __restrict__ m1g, const int* __restrict__ m2g,
                  float* __restrict__ rowmax_p, float* __restrict__ colmax_p)
{
    const int bid = blockIdx.x;
    const int l   = ((bid & 7) << 7) | (bid >> 3);
    const int b   = l >> 4;
    const int rt  = l & 3;
    const int ct  = (l >> 2) & 3;

    const int tid = threadIdx.x;
    const int lane = tid & 63;
    const int w    = tid >> 6;
    const int wm   = w >> 1;
    const int wn   = w & 1;
    const int q    = lane >> 4;
    const int ln   = lane & 15;
    const int nb   = ct * 128;

    __shared__ __align__(16) ushort sA[2][128 * 32];
    __shared__ __align__(16) ushort sB[2][128 * 32];
    float* spr   = reinterpret_cast<float*>(&sA[0][0]);
    float* spc   = reinterpret_cast<float*>(&sA[0][512]);
    int*   sm1   = reinterpret_cast<int*>(&sA[0][1024]);
    int*   sm2   = reinterpret_cast<int*>(&sA[0][1280]);
    float* sinv1 = reinterpret_cast<float*>(&sB[0][0]);
    float* sinv2 = reinterpret_cast<float*>(&sB[0][256]);

    const int r = tid >> 1;
    const int h = tid & 1;
    const int s = (r ^ (r >> 2)) & 3;
    const float* gA = e1 + ((size_t)(b * 512 + rt * 128 + r)) * 512 + h * 16;
    const float* gB = e2 + ((size_t)(b * 512 + nb + r)) * 512 + h * 16;
    const int wo0 = r * 32 + (((2 * h)     ^ s) << 3);
    const int wo1 = r * 32 + (((2 * h + 1) ^ s) << 3);

    const int sln = (ln & 3) ^ ((ln >> 2) & 3);
    int aoff[4], boff[4];
    #pragma unroll
    for (int mt = 0; mt < 4; ++mt)
        aoff[mt] = (wm * 64 + mt * 16 + ln) * 32 + ((q ^ sln) << 3);
    #pragma unroll
    for (int nt = 0; nt < 4; ++nt)
        boff[nt] = (wn * 64 + nt * 16 + ln) * 32 + ((q ^ sln) << 3);

    float ssA = 0.f, ssB = 0.f;
    float4 ra[2][4], rb[2][4];

    auto LOADK = [&](int u, int kf) {
        const float4* pa = reinterpret_cast<const float4*>(gA + kf);
        const float4* pb = reinterpret_cast<const float4*>(gB + kf);
        ra[u][0] = pa[0]; ra[u][1] = pa[1]; ra[u][2] = pa[2]; ra[u][3] = pa[3];
        rb[u][0] = pb[0]; rb[u][1] = pb[1]; rb[u][2] = pb[2]; rb[u][3] = pb[3];
    };
    auto CVTWRITE = [&](int u, int pd) {
        #pragma unroll
        for (int i = 0; i < 4; ++i) {
            ssA += ra[u][i].x * ra[u][i].x + ra[u][i].y * ra[u][i].y
                 + ra[u][i].z * ra[u][i].z + ra[u][i].w * ra[u][i].w;
            ssB += rb[u][i].x * rb[u][i].x + rb[u][i].y * rb[u][i].y
                 + rb[u][i].z * rb[u][i].z + rb[u][i].w * rb[u][i].w;
        }
        uint4 v;
        v.x = packbf2_hw(ra[u][0].x, ra[u][0].y); v.y = packbf2_hw(ra[u][0].z, ra[u][0].w);
        v.z = packbf2_hw(ra[u][1].x, ra[u][1].y); v.w = packbf2_hw(ra[u][1].z, ra[u][1].w);
        *reinterpret_cast<uint4*>(&sA[pd][wo0]) = v;
        v.x = packbf2_hw(ra[u][2].x, ra[u][2].y); v.y = packbf2_hw(ra[u][2].z, ra[u][2].w);
        v.z = packbf2_hw(ra[u][3].x, ra[u][3].y); v.w = packbf2_hw(ra[u][3].z, ra[u][3].w);
        *reinterpret_cast<uint4*>(&sA[pd][wo1]) = v;
        v.x = packbf2_hw(rb[u][0].x, rb[u][0].y); v.y = packbf2_hw(rb[u][0].z, rb[u][0].w);
        v.z = packbf2_hw(rb[u][1].x, rb[u][1].y); v.w = packbf2_hw(rb[u][1].z, rb[u][1].w);
        *reinterpret_cast<uint4*>(&sB[pd][wo0]) = v;
        v.x = packbf2_hw(rb[u][2].x, rb[u][2].y); v.y = packbf2_hw(rb[u][2].z, rb[u][2].w);
        v.z = packbf2_hw(rb[u][3].x, rb[u][3].y); v.w = packbf2_hw(rb[u][3].z, rb[u][3].w);
        *reinterpret_cast<uint4*>(&sB[pd][wo1]) = v;
    };

    f32x4 acc[4][4];
    #pragma unroll
    for (int i = 0; i < 4; ++i)
        #pragma unroll
        for (int j = 0; j < 4; ++j)
            acc[i][j] = (f32x4){0.f, 0.f, 0.f, 0.f};

    LOADK(0, 0);
    CVTWRITE(0, 0);
    LOADK(1, 32);
    BAR();

#define HALF_ITER(P, K)                                                    \
    do {                                                                   \
        if ((K) < 14) LOADK(P, ((K) + 2) * 32);                            \
        bf16x8 af[4], bfr[4];                                              \
        _Pragma("unroll")                                                  \
        for (int mt = 0; mt < 4; ++mt)                                     \
            af[mt] = *reinterpret_cast<const bf16x8*>(&sA[P][aoff[mt]]);   \
        _Pragma("unroll")                                                  \
        for (int nt = 0; nt < 4; ++nt)                                     \
            bfr[nt] = *reinterpret_cast<const bf16x8*>(&sB[P][boff[nt]]);  \
        if ((K) < 15) CVTWRITE((P) ^ 1, (P) ^ 1);                          \
        _Pragma("unroll")                                                  \
        for (int mt = 0; mt < 4; ++mt)                                     \
            _Pragma("unroll")                                              \
            for (int nt = 0; nt < 4; ++nt)                                 \
                acc[mt][nt] = __builtin_amdgcn_mfma_f32_16x16x32_bf16(     \
                    af[mt], bfr[nt], acc[mt][nt], 0, 0, 0);                \
        BAR();                                                             \
    } while (0)

    for (int kk = 0; kk < 8; ++kk) {
        HALF_ITER(0, 2 * kk);
        HALF_ITER(1, 2 * kk + 1);
    }
#undef HALF_ITER

    if (tid < 128) sm1[tid] = m1g[b * 512 + rt * 128 + tid];
    else           sm2[tid - 128] = m2g[b * 512 + nb + (tid - 128)];
    ssA += __shfl_xor(ssA, 1);
    ssB += __shfl_xor(ssB, 1);
    if (h == 0) {
        sinv1[r] = 1.0f / fmaxf(sqrtf(ssA), 1e-8f);
        sinv2[r] = 1.0f / fmaxf(sqrtf(ssB), 1e-8f);
    }
    BAR();

    float invj[4];
    f32x4 invi[4];
    #pragma unroll
    for (int nt = 0; nt < 4; ++nt)
        invj[nt] = sinv2[wn * 64 + nt * 16 + ln];
    #pragma unroll
    for (int mt = 0; mt < 4; ++mt)
        #pragma unroll
        for (int rg = 0; rg < 4; ++rg)
            invi[mt][rg] = sinv1[wm * 64 + mt * 16 + q * 4 + rg];
    #pragma unroll
    for (int mt = 0; mt < 4; ++mt)
        #pragma unroll
        for (int nt = 0; nt < 4; ++nt)
            acc[mt][nt] = acc[mt][nt] * (invi[mt] * invj[nt]);

    #pragma unroll
    for (int mt = 0; mt < 4; ++mt) {
        #pragma unroll
        for (int rg = 0; rg < 4; ++rg) {
            float rm = NEGBIG;
            #pragma unroll
            for (int nt = 0; nt < 4; ++nt) {
                float v = sm2[wn * 64 + nt * 16 + ln] ? acc[mt][nt][rg] : NEGBIG;
                rm = fmaxf(rm, v);
            }
            rm = fmaxf(rm, __shfl_xor(rm, 1));
            rm = fmaxf(rm, __shfl_xor(rm, 2));
            rm = fmaxf(rm, __shfl_xor(rm, 4));
            rm = fmaxf(rm, __shfl_xor(rm, 8));
            if (ln == 0) spr[wn * 128 + wm * 64 + mt * 16 + q * 4 + rg] = rm;
        }
    }
    #pragma unroll
    for (int nt = 0; nt < 4; ++nt) {
        float cm = NEGBIG;
        #pragma unroll
        for (int mt = 0; mt < 4; ++mt)
            #pragma unroll
            for (int rg = 0; rg < 4; ++rg) {
                float v = sm1[wm * 64 + mt * 16 + q * 4 + rg] ? acc[mt][nt][rg] : NEGBIG;
                cm = fmaxf(cm, v);
            }
        cm = fmaxf(cm, __shfl_xor(cm, 16));
        cm = fmaxf(cm, __shfl_xor(cm, 32));
        if (lane < 16) spc[wm * 128 + wn * 64 + nt * 16 + ln] = cm;
    }
    BAR();
    if (tid < 128) {
        rowmax_p[((size_t)b * 4 + ct) * 512 + rt * 128 + tid] =
            fmaxf(spr[tid], spr[128 + tid]);
        colmax_p[((size_t)b * 4 + rt) * 512 + nb + tid] =
            fmaxf(spc[tid], spc[128 + tid]);
    }
}

// ---------------- kernel 2: per-batch final reduction ----------------
__global__ __launch_bounds__(256)
void final_kernel(const int* __restrict__ m1g, const int* __restrict__ m2g,
                  const float* __restrict__ rowmax_p, const float* __restrict__ colmax_p,
                  float* __restrict__ out)
{
    const int b = blockIdx.x;
    const int tid = threadIdx.x;
    const int lane = tid & 63;
    const int w = tid >> 6;

    float sum = 0.f;
    float nn  = 0.f;
    for (int j = tid; j < 512; j += 256) {
        int mm1 = m1g[b * 512 + j];
        int mm2 = m2g[b * 512 + j];
        nn += (float)(mm1 + mm2);
        const float* rp = rowmax_p + (size_t)b * 2048 + j;
        float rm = fmaxf(fmaxf(rp[0], rp[512]), fmaxf(rp[1024], rp[1536]));
        if (mm1) sum += rm;
        const float* cp = colmax_p + (size_t)b * 2048 + j;
        float cm = fmaxf(fmaxf(cp[0], cp[512]), fmaxf(cp[1024], cp[1536]));
        if (mm2) sum += cm;
    }
    #pragma unroll
    for (int m = 32; m; m >>= 1) {
        sum += __shfl_xor(sum, m);
        nn  += __shfl_xor(nn, m);
    }
    __shared__ float ssum[4], snn[4];
    if (lane == 0) { ssum[w] = sum; snn[w] = nn; }
    __syncthreads();
    if (tid == 0) {
        float S = ssum[0] + ssum[1] + ssum[2] + ssum[3];
        float N = snn[0] + snn[1] + snn[2] + snn[3];
        out[b] = S / N;
    }
}

extern "C" void kernel_launch(void* const* d_in, const int* in_sizes, int n_in,
                              void* d_out, int out_size, void* d_ws, size_t ws_size,
                              hipStream_t stream) {
    const float* e1 = (const float*)d_in[0];
    const float* e2 = (const float*)d_in[1];
    const int*   m1 = (const int*)d_in[2];
    const int*   m2 = (const int*)d_in[3];
    float* out = (float*)d_out;

    float* ws = (float*)d_ws;
    float* rowmax_p = ws;                 // 64*4*512 floats
    float* colmax_p = ws + 131072;        // 64*4*512 floats

    const size_t PANEL = (size_t)64 * 512 * 512;            // ushort count
    const size_t NEED  = 1048576 + 2 * PANEL * sizeof(ushort);  // ~68.1 MB

    if (ws_size >= NEED) {
        ushort* e1n = (ushort*)((char*)d_ws + 1048576);
        ushort* e2n = e1n + PANEL;
        prep_kernel<<<dim3(1024), 256, 0, stream>>>(e1, e2, e1n, e2n);
        sim_gemm<<<dim3(1024), 256, 0, stream>>>(e1n, e2n, m1, m2,
                                                 rowmax_p, colmax_p);
    } else {
        sim_fused_fb<<<dim3(1024), 256, 0, stream>>>(e1, e2, m1, m2,
                                                     rowmax_p, colmax_p);
    }
    final_kernel<<<64, 256, 0, stream>>>(m1, m2, rowmax_p, colmax_p, out);
}